// Round 13
// baseline (460.665 us; speedup 1.0000x reference)
//
#include <hip/hip_runtime.h>
#include <stdint.h>

#define E_ 8
#define M_ 8192
#define K_ 2048
#define N_ 8192

#define BM 256
#define BN 256
#define BK 64
#define NT (K_ / BK)        // 32 K-tiles
#define LDS_BYTES 131072    // 2 dbuf x 64KB

typedef __attribute__((ext_vector_type(8))) short bf16x8;
typedef __attribute__((ext_vector_type(16))) float f32x16;
typedef __attribute__((ext_vector_type(8))) unsigned short us8;

__device__ __forceinline__ unsigned short f2bf(float f) {
  union { float f; uint32_t u; } v; v.f = f;
  uint32_t u = v.u;
  uint32_t r = (u + 0x7FFFu + ((u >> 16) & 1u)) >> 16;
  return (unsigned short)r;
}

__device__ __forceinline__ void gload_lds16(const void* g, void* l) {
  __builtin_amdgcn_global_load_lds(
      (const __attribute__((address_space(1))) unsigned int*)g,
      (__attribute__((address_space(3))) unsigned int*)l,
      16, 0, 0);
}

// ---------------- fp32 -> bf16, layout preserving (inputs) ----------------
__global__ __launch_bounds__(256) void conv_a(const float* __restrict__ A,
                                              unsigned short* __restrict__ Ab,
                                              int n8) {
  int stride = gridDim.x * blockDim.x;
  for (int idx = blockIdx.x * blockDim.x + threadIdx.x; idx < n8; idx += stride) {
    const float4* p = reinterpret_cast<const float4*>(A) + (size_t)idx * 2;
    float4 x0 = p[0], x1 = p[1];
    us8 o;
    o[0] = f2bf(x0.x); o[1] = f2bf(x0.y); o[2] = f2bf(x0.z); o[3] = f2bf(x0.w);
    o[4] = f2bf(x1.x); o[5] = f2bf(x1.y); o[6] = f2bf(x1.z); o[7] = f2bf(x1.w);
    *reinterpret_cast<us8*>(Ab + (size_t)idx * 8) = o;
  }
}

// ------------- fp32 W[e][K][N] -> bf16 Wt[e][N][K] (transpose) -------------
__global__ __launch_bounds__(256) void conv_wT(const float* __restrict__ W,
                                               unsigned short* __restrict__ Wt,
                                               int e_fixed) {
  __shared__ float t[64][65];
  int tid = threadIdx.x;
  int tx = tid & 63, ty = tid >> 6;
  int n0 = blockIdx.x * 64, k0 = blockIdx.y * 64;
  int e = (gridDim.z > 1) ? blockIdx.z : e_fixed;
  size_t win = (size_t)e * K_ * N_;
  size_t wout = (gridDim.z > 1) ? win : 0;

  #pragma unroll
  for (int r = 0; r < 16; ++r) {
    int kl = r * 4 + ty;
    t[kl][tx] = W[win + (size_t)(k0 + kl) * N_ + n0 + tx];
  }
  __syncthreads();
  int px = tid & 31, py = tid >> 5;
  #pragma unroll
  for (int r = 0; r < 8; ++r) {
    int nl = r * 8 + py;
    unsigned int pack = (unsigned int)f2bf(t[2 * px][nl]) |
                        ((unsigned int)f2bf(t[2 * px + 1][nl]) << 16);
    *reinterpret_cast<unsigned int*>(Wt + wout + (size_t)(n0 + nl) * K_ + k0 + 2 * px) = pack;
  }
}

// -- grouped bf16 GEMM: 256x256, BK=64, dbuf-2, R5 4-phase, MFMA 32x32x16 --
// LDS dbuf d at d*65536: A @0 (256 rows x 128B), B @32768 (256 rows x 128B).
// Row r: 8 slots of 16B; logical slot q at phys q ^ (r&7) (verified 0-conflict).
// Fragment slot index = kk*4 + ks*2 + (lane>>5); byte = slot032 ^ ks<<5 ^ kk<<6.
// A/B operand: row|col = lane&31, k = (lane>>5)*8+j (sym. of verified 16x16).
// C/D: col = lane&31, row = (reg&3)+8*(reg>>2)+4*(lane>>5)  [m74/m101].
// Phases: P0 (kk0, mi01 +B kk0), P1 (kk0, mi23), P2 (kk1, mi01 +B kk1),
// P3 (kk1, mi23); 8 MFMA each. Stage B0B1|B2B3|A0A2|A1A3; vmcnt(2) at P0/P3.
__global__ __launch_bounds__(512, 2) void moe_gemm_bf16(
    const unsigned short* __restrict__ Ab,   // [M][K] bf16
    const unsigned short* __restrict__ Wt,   // [e][N][K] bf16
    const int* __restrict__ gs,
    const float* __restrict__ bias,
    float* __restrict__ C,
    int only_expert, size_t wt_stride) {
  extern __shared__ char smem[];

  int tile_n = blockIdx.x;
  int tile_m = blockIdx.y;

  int expert = -1, row_start = 0, rows = 0;
  if (only_expert >= 0) {
    int off = 0;
    for (int e = 0; e < only_expert; ++e) off += gs[e];
    int g = gs[only_expert];
    int t0 = tile_m * BM;
    if (t0 >= g) return;
    expert = only_expert;
    row_start = off + t0;
    rows = min(BM, g - t0);
  } else {
    int acc = 0, off = 0;
    for (int e = 0; e < E_; ++e) {
      int g = gs[e];
      int t = (g + BM - 1) / BM;
      if (expert < 0 && tile_m < acc + t) {
        int lt = tile_m - acc;
        expert = e;
        row_start = off + lt * BM;
        rows = min(BM, g - lt * BM);
      }
      acc += t;
      off += g;
    }
    if (expert < 0) return;
  }

  const unsigned short* WtE = Wt + (size_t)expert * wt_stride;

  int tid = threadIdx.x;          // 0..511
  int lane = tid & 63;
  int wave = tid >> 6;            // 0..7
  int wr = wave >> 2;             // 0..1 (M half: 128 rows)
  int wc = wave & 3;              // 0..3 (N quarter: 64 cols)
  int bh = wc >> 1;
  int ln31 = lane & 31;
  int l5 = lane >> 5;             // 0..1
  int n0 = tile_n * BN;

  // ---- fragment read bases ----
  int slot032 = ((l5 ^ (lane & 7)) << 4);          // ^ (ks<<5) ^ (kk<<6)
  int aBase = wr * 16384 + ln31 * 128;             // + mi*4096
  int bBase = 32768 + (bh * 128 + (wc & 1) * 64 + ln31) * 128;  // + nj*4096

  // ---- staging precompute: thread stages 16B of each 8KB (64-row) chunk ----
  int soff = tid * 16;
  int crow = tid >> 3;            // 0..63
  int lslot = (tid & 7) ^ (crow & 7);
  int scol = lslot * 8;

  const unsigned short* aS[4];
  const unsigned short* bS[4];
  #pragma unroll
  for (int c = 0; c < 4; ++c) {
    int r = c * 64 + crow;
    int gr = r < rows ? r : 0;     // clamp partial M tiles
    aS[c] = Ab + (size_t)(row_start + gr) * K_ + scol;
    bS[c] = WtE + (size_t)(n0 + r) * K_ + scol;
  }

#define STG_A(DB, c, kt) \
  gload_lds16(aS[c] + (kt) * 64, smem + (DB) + (c) * 8192 + soff)
#define STG_B(DB, c, kt) \
  gload_lds16(bS[c] + (kt) * 64, smem + (DB) + 32768 + (c) * 8192 + soff)

  f32x16 acc4[4][2];
  #pragma unroll
  for (int i = 0; i < 4; ++i)
    #pragma unroll
    for (int j = 0; j < 2; ++j)
      #pragma unroll
      for (int r = 0; r < 16; ++r) acc4[i][j][r] = 0.f;

#define DS_A2(frag, DB, KK, MIB)                                              \
  _Pragma("unroll") for (int m = 0; m < 2; ++m)                               \
    _Pragma("unroll") for (int ks = 0; ks < 2; ++ks)                          \
      frag[m][ks] = *(const bf16x8*)(smem + (DB) + aBase + ((MIB) + m) * 4096 \
                                     + (slot032 ^ (ks << 5) ^ ((KK) << 6)));
#define DS_B2(frag, DB, KK)                                                   \
  _Pragma("unroll") for (int nj = 0; nj < 2; ++nj)                            \
    _Pragma("unroll") for (int ks = 0; ks < 2; ++ks)                          \
      frag[nj][ks] = *(const bf16x8*)(smem + (DB) + bBase + nj * 4096         \
                                      + (slot032 ^ (ks << 5) ^ ((KK) << 6)));
#define MFMA8(MIB, afr, bfr)                                                  \
  __builtin_amdgcn_s_setprio(1);                                              \
  _Pragma("unroll") for (int ks = 0; ks < 2; ++ks)                            \
    _Pragma("unroll") for (int m = 0; m < 2; ++m)                             \
      _Pragma("unroll") for (int nj = 0; nj < 2; ++nj)                        \
        acc4[(MIB) + m][nj] = __builtin_amdgcn_mfma_f32_32x32x16_bf16(        \
            afr[m][ks], bfr[nj][ks], acc4[(MIB) + m][nj], 0, 0, 0);           \
  __builtin_amdgcn_s_setprio(0);

  // Per K-tile: P0 (kk0, mi 0-1 +B), P1 (kk0, mi 2-3), P2 (kk1, mi 0-1 +B),
  // P3 (kk1, mi 2-3). Stage next tile: B0,B1 | B2,B3 | A0,A2 | A1,A3.
#define TILE4(DB, DBN, KTN)                                                   \
  do {                                                                        \
    bf16x8 af[2][2], bf[2][2];                                                \
    /* P0 */                                                                  \
    DS_A2(af, DB, 0, 0); DS_B2(bf, DB, 0);                                    \
    STG_B(DBN, 0, KTN); STG_B(DBN, 1, KTN);                                   \
    __builtin_amdgcn_s_barrier();                                             \
    asm volatile("s_waitcnt lgkmcnt(0)" ::: "memory");                        \
    __builtin_amdgcn_sched_barrier(0);                                        \
    MFMA8(0, af, bf);                                                         \
    asm volatile("s_waitcnt vmcnt(2)" ::: "memory");                          \
    __builtin_amdgcn_s_barrier();                                             \
    /* P1 (B reused in regs) */                                               \
    DS_A2(af, DB, 0, 2);                                                      \
    STG_B(DBN, 2, KTN); STG_B(DBN, 3, KTN);                                   \
    __builtin_amdgcn_s_barrier();                                             \
    asm volatile("s_waitcnt lgkmcnt(0)" ::: "memory");                        \
    __builtin_amdgcn_sched_barrier(0);                                        \
    MFMA8(2, af, bf);                                                         \
    __builtin_amdgcn_s_barrier();                                             \
    /* P2 */                                                                  \
    DS_A2(af, DB, 1, 0); DS_B2(bf, DB, 1);                                    \
    STG_A(DBN, 0, KTN); STG_A(DBN, 2, KTN);                                   \
    __builtin_amdgcn_s_barrier();                                             \
    asm volatile("s_waitcnt lgkmcnt(0)" ::: "memory");                        \
    __builtin_amdgcn_sched_barrier(0);                                        \
    MFMA8(0, af, bf);                                                         \
    __builtin_amdgcn_s_barrier();                                             \
    /* P3 */                                                                  \
    DS_A2(af, DB, 1, 2);                                                      \
    STG_A(DBN, 1, KTN); STG_A(DBN, 3, KTN);                                   \
    __builtin_amdgcn_s_barrier();                                             \
    asm volatile("s_waitcnt lgkmcnt(0)" ::: "memory");                        \
    __builtin_amdgcn_sched_barrier(0);                                        \
    MFMA8(2, af, bf);                                                         \
    asm volatile("s_waitcnt vmcnt(2)" ::: "memory");                          \
    __builtin_amdgcn_s_barrier();                                             \
  } while (0)

  // prologue: stage tile 0 into dbuf0 in consumption order
  STG_B(0, 0, 0); STG_B(0, 1, 0); STG_B(0, 2, 0); STG_B(0, 3, 0);
  STG_A(0, 0, 0); STG_A(0, 2, 0);
  STG_A(0, 1, 0); STG_A(0, 3, 0);
  asm volatile("s_waitcnt vmcnt(2)" ::: "memory");  // first 6 chunks landed
  __builtin_amdgcn_s_barrier();

  for (int t2 = 0; t2 < NT; t2 += 2) {
    int k2 = (t2 + 2 >= NT) ? 0 : t2 + 2;  // wrap: dead stores, uniform counts
    TILE4(0, 65536, t2 + 1);
    TILE4(65536, 0, k2);
  }
#undef TILE4
#undef DS_A2
#undef DS_B2
#undef MFMA8
#undef STG_A
#undef STG_B

  asm volatile("s_waitcnt vmcnt(0)" ::: "memory");  // drain wrapped tail stages

  // epilogue: C = acc + bias ; 32x32 C/D: col=lane&31,
  // row = (reg&3) + 8*(reg>>2) + 4*(lane>>5)
  float bv[2];
  #pragma unroll
  for (int nj = 0; nj < 2; ++nj) bv[nj] = bias[n0 + wc * 64 + nj * 32 + ln31];
  #pragma unroll
  for (int mi = 0; mi < 4; ++mi) {
    #pragma unroll
    for (int g = 0; g < 4; ++g) {
      #pragma unroll
      for (int rb = 0; rb < 4; ++rb) {
        int reg = g * 4 + rb;
        int lr = wr * 128 + mi * 32 + rb + g * 8 + l5 * 4;
        if (lr < rows) {
          float* Cp = C + (size_t)(row_start + lr) * N_ + n0 + wc * 64 + ln31;
          #pragma unroll
          for (int nj = 0; nj < 2; ++nj) Cp[nj * 32] = acc4[mi][nj][reg] + bv[nj];
        }
      }
    }
  }
}

// ---------------- naive fp32 fallback (only if workspace too small) ----------------
__global__ __launch_bounds__(256) void moe_naive(const float* __restrict__ A,
                                                 const float* __restrict__ W,
                                                 const int* __restrict__ gs,
                                                 const float* __restrict__ bias,
                                                 float* __restrict__ C) {
  int col = blockIdx.x * 16 + (threadIdx.x & 15);
  int row = blockIdx.y * 16 + (threadIdx.x >> 4);
  int acc = 0, e = E_ - 1;
  for (int i = 0; i < E_; ++i) {
    int g = gs[i];
    if (row >= acc && row < acc + g) { e = i; break; }
    acc += g;
  }
  const float* a = A + (size_t)row * K_;
  const float* w = W + (size_t)e * K_ * N_ + col;
  float s = 0.f;
  for (int k = 0; k < K_; ++k) s += a[k] * w[(size_t)k * N_];
  C[(size_t)row * N_ + col] = s + bias[col];
}

extern "C" void kernel_launch(void* const* d_in, const int* in_sizes, int n_in,
                              void* d_out, int out_size, void* d_ws, size_t ws_size,
                              hipStream_t stream) {
  const float* A = (const float*)d_in[0];
  const float* W = (const float*)d_in[1];
  const int* gs = (const int*)d_in[2];
  const float* bias = (const float*)d_in[3];
  float* C = (float*)d_out;

  const size_t needA = (size_t)M_ * K_ * 2;          // 32 MiB
  const size_t needWall = (size_t)E_ * K_ * N_ * 2;  // 256 MiB
  const size_t needW1 = (size_t)K_ * N_ * 2;         // 32 MiB

  (void)hipFuncSetAttribute((const void*)moe_gemm_bf16,
                            hipFuncAttributeMaxDynamicSharedMemorySize, LDS_BYTES);

  if (ws_size >= needA + needWall) {
    unsigned short* Abf = (unsigned short*)d_ws;
    unsigned short* Wtb = (unsigned short*)((char*)d_ws + needA);
    conv_a<<<2048, 256, 0, stream>>>(A, Abf, (M_ * K_) / 8);
    dim3 gw(N_ / 64, K_ / 64, E_);
    conv_wT<<<gw, 256, 0, stream>>>(W, Wtb, 0);
    dim3 gg(N_ / BN, M_ / BM + E_);
    moe_gemm_bf16<<<gg, 512, LDS_BYTES, stream>>>(Abf, Wtb, gs, bias, C, -1, (size_t)N_ * K_);
  } else if (ws_size >= needA + needW1) {
    unsigned short* Abf = (unsigned short*)d_ws;
    unsigned short* Wtb = (unsigned short*)((char*)d_ws + needA);
    conv_a<<<2048, 256, 0, stream>>>(A, Abf, (M_ * K_) / 8);
    for (int e = 0; e < E_; ++e) {
      dim3 gw(N_ / 64, K_ / 64, 1);
      conv_wT<<<gw, 256, 0, stream>>>(W, Wtb, e);
      dim3 gg(N_ / BN, M_ / BM);
      moe_gemm_bf16<<<gg, 512, LDS_BYTES, stream>>>(Abf, Wtb, gs, bias, C, e, 0);
    }
  } else {
    dim3 gn(N_ / 16, M_ / 16);
    moe_naive<<<gn, 256, 0, stream>>>(A, W, gs, bias, C);
  }
}